// Round 13
// baseline (240.981 us; speedup 1.0000x reference)
//
#include <hip/hip_runtime.h>

#define BATCH 32768
#define SEQLEN 12
#define NBLK 1024   // 128 threads = 2 waves; each wave privately owns 16 peds (2 scenes)

typedef short short8 __attribute__((ext_vector_type(8)));
typedef float f32x4 __attribute__((ext_vector_type(4)));
typedef unsigned short ushort_t;

static __device__ __forceinline__ unsigned short f2bf(float x) {
    unsigned u = __float_as_uint(x);
    return (unsigned short)((u + 0x7FFFu + ((u >> 16) & 1u)) >> 16);  // RNE
}
static __device__ __forceinline__ float bf2f(unsigned short h) {
    return __uint_as_float(((unsigned)h) << 16);
}

#define MFMA __builtin_amdgcn_mfma_f32_16x16x32_bf16

// max with DPP partner (VALU). quad_perm xor1=0xB1, xor2=0x4E,
// row_half_mirror=0x141 (xor4-equivalent after xor1/xor2 for 8-lane max).
// All three verified in r11 (passed, absmax 0.001953125).
#define FMAXDPP(X, CTRL) \
    fmaxf((X), __int_as_float(__builtin_amdgcn_mov_dpp(__float_as_int(X), (CTRL), 0xF, 0xF, true)))

// Wave-private v10. r12 failed (absmax 6.98e-2): the hand-rolled
// permlane16/32_swap WSUM inline asm — both "+v" operands init'd from the
// SAME value can be allocated to ONE physical register (no earlyclobber),
// degenerating the swap to a row-mirror -> pv = 2*mirror instead of the sum.
// v10 reverts ONLY that: h2p reduction back to r11-verified __shfl_xor(16/32).
// Everything else from r12 stands (each piece value-identical to r11):
// register-resident hi-weight MFMA streams (c2h 48, c3h 24 regs) + lo weights
// (a3 compensation only) in LDS; (128,2) -> 2 waves/SIMD, 1024 blocks fully
// resident in one round; conv1 base precomputed off the r0-dependent path.

#define F4FMA(ACC, X, S) do {                                                 \
    (ACC).x = fmaf((X).x, (S), (ACC).x); (ACC).y = fmaf((X).y, (S), (ACC).y); \
    (ACC).z = fmaf((X).z, (S), (ACC).z); (ACC).w = fmaf((X).w, (S), (ACC).w); \
} while(0)

// conv1 base part (K1 + A0*pax + B0*pay + A1*pbx + B1*pby), k-major streamed.
// Writes baseL[2]/baseH[2] (declared by caller). FMA order == verified C1PED.
#define C1BASE(PA_, PB_) do {                                                 \
    _Pragma("unroll")                                                         \
    for (int ich_ = 0; ich_ < 2; ++ich_) {                                    \
        const float* ct_ = &c1t7[0][ich_*32 + kg*8];                          \
        float4 aL_ = *(const float4*)(ct_ + 6*64);                            \
        float4 aH_ = *(const float4*)(ct_ + 6*64 + 4);                        \
        float4 xL_ = *(const float4*)(ct_ + 0*64);                            \
        float4 xH_ = *(const float4*)(ct_ + 0*64 + 4);                        \
        F4FMA(aL_, xL_, (PA_).x); F4FMA(aH_, xH_, (PA_).x);                   \
        xL_ = *(const float4*)(ct_ + 1*64); xH_ = *(const float4*)(ct_ + 1*64 + 4); \
        F4FMA(aL_, xL_, (PA_).y); F4FMA(aH_, xH_, (PA_).y);                   \
        xL_ = *(const float4*)(ct_ + 2*64); xH_ = *(const float4*)(ct_ + 2*64 + 4); \
        F4FMA(aL_, xL_, (PB_).x); F4FMA(aH_, xH_, (PB_).x);                   \
        xL_ = *(const float4*)(ct_ + 3*64); xH_ = *(const float4*)(ct_ + 3*64 + 4); \
        F4FMA(aL_, xL_, (PB_).y); F4FMA(aH_, xH_, (PB_).y);                   \
        baseL[ich_] = aL_; baseH[ich_] = aH_;                                 \
    }                                                                         \
} while(0)

// conv1 finish: + A2*r0 + B2*r1, relu, hi/lo pack -> s1 reg frag slot SL_.
#define C1FIN(R0_, R1_, SL_) do {                                             \
    _Pragma("unroll")                                                         \
    for (int ich_ = 0; ich_ < 2; ++ich_) {                                    \
        const float* ct_ = &c1t7[0][ich_*32 + kg*8];                          \
        float4 a2L_ = *(const float4*)(ct_ + 4*64);                           \
        float4 a2H_ = *(const float4*)(ct_ + 4*64 + 4);                       \
        float4 b2L_ = *(const float4*)(ct_ + 5*64);                           \
        float4 b2H_ = *(const float4*)(ct_ + 5*64 + 4);                       \
        short8 sh_, sl_;                                                      \
        _Pragma("unroll")                                                     \
        for (int j_ = 0; j_ < 4; ++j_) {                                      \
            float v_ = fmaf(((const float*)&a2L_)[j_], (R0_),                 \
                            ((const float*)&baseL[ich_])[j_]);                \
            v_ = fmaf(((const float*)&b2L_)[j_], (R1_), v_);                  \
            v_ = fmaxf(v_, 0.f);                                              \
            ushort_t h_ = f2bf(v_);                                           \
            sh_[j_] = (short)h_;                                              \
            sl_[j_] = (short)f2bf(v_ - bf2f(h_));                             \
        }                                                                     \
        _Pragma("unroll")                                                     \
        for (int j_ = 0; j_ < 4; ++j_) {                                      \
            float v_ = fmaf(((const float*)&a2H_)[j_], (R0_),                 \
                            ((const float*)&baseH[ich_])[j_]);                \
            v_ = fmaf(((const float*)&b2H_)[j_], (R1_), v_);                  \
            v_ = fmaxf(v_, 0.f);                                              \
            ushort_t h_ = f2bf(v_);                                           \
            sh_[4+j_] = (short)h_;                                            \
            sl_[4+j_] = (short)f2bf(v_ - bf2f(h_));                           \
        }                                                                     \
        s1fh[SL_][ich_] = sh_; s1fl[SL_][ich_] = sl_;                         \
    }                                                                         \
} while(0)

// warm-up: full conv1 column from pos ring taps
#define C1FULL(SA_, SB_, SC_, SL_) do {                                       \
    float2 pa_ = *(const float2*)&pos_s[wv][SA_][n][0];                       \
    float2 pb_ = *(const float2*)&pos_s[wv][SB_][n][0];                       \
    float2 pc_ = *(const float2*)&pos_s[wv][SC_][n][0];                       \
    float4 baseL[2], baseH[2];                                                \
    C1BASE(pa_, pb_);                                                         \
    C1FIN(pc_.x, pc_.y, SL_);                                                 \
} while(0)

// conv2 column c (c%3 == CM3): s1 reg frags x (hi regs, lo LDS) -> s2 stage
// -> reg frag slot CM3. Numerics identical to verified r11.
#define CONV2COL(CM3) do {                                                    \
    const float* b2b_ = &b2s[0];                                              \
    asm volatile("" : "+v"(b2b_));                                            \
    _Pragma("unroll")                                                         \
    for (int T = 0; T < 2; ++T) {                                             \
        f32x4 a1 = {0.f,0.f,0.f,0.f}, a2 = {0.f,0.f,0.f,0.f},                 \
              a3 = {0.f,0.f,0.f,0.f};                                         \
        _Pragma("unroll")                                                     \
        for (int kb = 0; kb < 6; ++kb) {                                      \
            const int sl = ((CM3) + (kb >> 1)) % 3, ich = kb & 1;             \
            const short8 wl = *(const short8*)&c2wl[T*6+kb][lane][0];         \
            a1 = MFMA(c2h[T][kb], s1fh[sl][ich], a1, 0, 0, 0);                \
            a2 = MFMA(c2h[T][kb], s1fl[sl][ich], a2, 0, 0, 0);                \
            a3 = MFMA(wl, s1fh[sl][ich], a3, 0, 0, 0);                        \
        }                                                                     \
        const float4 bb = *(const float4*)&b2b_[T*16 + kg*4];                 \
        float w0 = fmaxf(a1[0]+a2[0]+a3[0]+bb.x, 0.f);                        \
        float w1 = fmaxf(a1[1]+a2[1]+a3[1]+bb.y, 0.f);                        \
        float w2 = fmaxf(a1[2]+a2[2]+a3[2]+bb.z, 0.f);                        \
        float w3 = fmaxf(a1[3]+a2[3]+a3[3]+bb.w, 0.f);                        \
        ushort_t h0=f2bf(w0), h1=f2bf(w1), h2=f2bf(w2), h3=f2bf(w3);          \
        *(uint2*)&s2sh[wv][n][T*16 + kg*4] = make_uint2(                      \
            (unsigned)h0 | ((unsigned)h1 << 16),                              \
            (unsigned)h2 | ((unsigned)h3 << 16));                             \
        *(uint2*)&s2sl[wv][n][T*16 + kg*4] = make_uint2(                      \
            (unsigned)f2bf(w0-bf2f(h0)) | ((unsigned)f2bf(w1-bf2f(h1)) << 16),\
            (unsigned)f2bf(w2-bf2f(h2)) | ((unsigned)f2bf(w3-bf2f(h3)) << 16));\
    }                                                                         \
    s2fh[(CM3)] = *(const short8*)&s2sh[wv][n][kg*8];                         \
    s2fl[(CM3)] = *(const short8*)&s2sl[wv][n][kg*8];                         \
} while(0)

// conv3 column v (v%3 == VM3, v&1 == PARI): s2 reg frags x (hi regs, lo LDS).
// Scene-max fully VALU (quad DPP + half-mirror), r11-verified.
#define CONV3COL(VM3, PARI) do {                                              \
    const float* b3b_ = &b3s[0];                                              \
    asm volatile("" : "+v"(b3b_));                                            \
    _Pragma("unroll")                                                         \
    for (int T = 0; T < 2; ++T) {                                             \
        f32x4 a1 = {0.f,0.f,0.f,0.f}, a2 = {0.f,0.f,0.f,0.f},                 \
              a3 = {0.f,0.f,0.f,0.f};                                         \
        _Pragma("unroll")                                                     \
        for (int kb = 0; kb < 3; ++kb) {                                      \
            const int sl = ((VM3) + kb) % 3;                                  \
            const short8 wl = *(const short8*)&c3wl[T*3+kb][lane][0];         \
            a1 = MFMA(c3h[T][kb], s2fh[sl], a1, 0, 0, 0);                     \
            a2 = MFMA(c3h[T][kb], s2fl[sl], a2, 0, 0, 0);                     \
            a3 = MFMA(wl, s2fh[sl], a3, 0, 0, 0);                             \
        }                                                                     \
        const float4 b3v = *(const float4*)&b3b_[T*16 + kg*4];                \
        float m0 = fmaxf(a1[0]+a2[0]+a3[0]+b3v.x, 0.f);                       \
        float m1 = fmaxf(a1[1]+a2[1]+a3[1]+b3v.y, 0.f);                       \
        float m2 = fmaxf(a1[2]+a2[2]+a3[2]+b3v.z, 0.f);                       \
        float m3 = fmaxf(a1[3]+a2[3]+a3[3]+b3v.w, 0.f);                       \
        c3c[PARI][T] = (f32x4){m0, m1, m2, m3};                               \
        m0 = FMAXDPP(m0, 0xB1); m0 = FMAXDPP(m0, 0x4E); m0 = FMAXDPP(m0, 0x141);\
        m1 = FMAXDPP(m1, 0xB1); m1 = FMAXDPP(m1, 0x4E); m1 = FMAXDPP(m1, 0x141);\
        m2 = FMAXDPP(m2, 0xB1); m2 = FMAXDPP(m2, 0x4E); m2 = FMAXDPP(m2, 0x141);\
        m3 = FMAXDPP(m3, 0xB1); m3 = FMAXDPP(m3, 0x4E); m3 = FMAXDPP(m3, 0x141);\
        mxc[PARI][T] = (f32x4){m0, m1, m2, m3};                               \
    }                                                                         \
} while(0)

// stage obs taus T0,T0+1 into pos ring (slot = tau&3)
#define STAGE2(T0) do {                                                       \
    const int tau_ = (T0) + (lane >> 5);                                      \
    const int p_ = (lane >> 1) & 15, c_ = lane & 1;                           \
    pos_s[wv][tau_ & 3][p_][c_] =                                             \
        obs[(size_t)(tau_*BATCH + bped + p_)*2 + c_];                         \
} while(0)

// one recurrent step: h2p(st) -> conv1(st+6) -> conv2(st+4) -> conv3(st+2)
#define STEP(K) do {                                                          \
    const int st = sbase + (K);                                               \
    float2 c1pa = *(const float2*)&pos_s[wv][(st+2)&3][n][0];                 \
    float2 c1pb = *(const float2*)&pos_s[wv][(st+3)&3][n][0];                 \
    float4 baseL[2], baseH[2];                                                \
    C1BASE(c1pa, c1pb);    /* conv1 base: off the r0-dependent path */        \
    float pv0a = 0.f, pv0b = 0.f, pv1a = 0.f, pv1b = 0.f;                     \
    {                                                                         \
        const float* wqf_ = &whp_s[kg][0];                                    \
        asm volatile("" : "+v"(wqf_));  /* defeat 64-reg invariant hoist */   \
        const float4* wq = (const float4*)wqf_;                               \
        _Pragma("unroll")                                                     \
        for (int q = 0; q < 16; ++q) {                                        \
            float4 ww = wq[q];                                                \
            _Pragma("unroll")                                                 \
            for (int e = 0; e < 4; ++e) {                                     \
                const int j2 = (q & 7)*4 + e;                                 \
                const int jj = j2 & 15;                                       \
                const int T = jj >> 3, r = (jj >> 1) & 3, col = jj & 1;       \
                const int par = col ? (((K)+1) & 1) : ((K) & 1);              \
                float val = (j2 < 16) ? c3c[par][T][r] : mxc[par][T][r];      \
                float wv_ = (e==0)?ww.x:(e==1)?ww.y:(e==2)?ww.z:ww.w;         \
                if (q < 8) { if (q & 1) pv0b = fmaf(wv_, val, pv0b);          \
                             else       pv0a = fmaf(wv_, val, pv0a); }        \
                else       { if (q & 1) pv1b = fmaf(wv_, val, pv1b);          \
                             else       pv1a = fmaf(wv_, val, pv1a); }        \
            }                                                                 \
        }                                                                     \
    }                                                                         \
    float pv0 = pv0a + pv0b, pv1 = pv1a + pv1b;                               \
    pv0 += __shfl_xor(pv0, 16); pv0 += __shfl_xor(pv0, 32);                   \
    pv1 += __shfl_xor(pv1, 16); pv1 += __shfl_xor(pv1, 32);                   \
    const float r0 = pv0 + bhp0, r1 = pv1 + bhp1;                             \
    if (lane < 16) {                                                          \
        float2 o; o.x = r0; o.y = r1;                                         \
        *(float2*)&out[(size_t)(st*BATCH + bped + lane)*2] = o;               \
    }                                                                         \
    if (st < SEQLEN-1) {                                                      \
        if (lane < 16) {                                                      \
            float2 o2; o2.x = r0; o2.y = r1;                                  \
            *(float2*)&pos_s[wv][st & 3][lane][0] = o2;   /* tau st+8 */      \
        }                                                                     \
        C1FIN(r0, r1, (K)%3);                        /* col st+6 */           \
        CONV2COL(((K)+1)%3);                         /* col st+4 */           \
        CONV3COL(((K)+2)%3, (K)&1);                  /* col st+2 */           \
    }                                                                         \
} while(0)

__global__ __launch_bounds__(128, 2)
void enc_wp(const float* __restrict__ obs,
            const float* __restrict__ Wse, const float* __restrict__ bse,
            const float* __restrict__ v1, const float* __restrict__ g1, const float* __restrict__ b1,
            const float* __restrict__ v2, const float* __restrict__ g2, const float* __restrict__ b2,
            const float* __restrict__ v3, const float* __restrict__ g3, const float* __restrict__ b3,
            const float* __restrict__ Whp, const float* __restrict__ bhp,
            float* __restrict__ out)
{
    __shared__ __align__(16) ushort_t c2wl[12][64][8];                  // 12288 B (lo weights)
    __shared__ __align__(16) ushort_t c3wl[6][64][8];                   //  6144 B (lo weights)
    __shared__ __align__(16) ushort_t s2sh[2][16][40], s2sl[2][16][40]; //  5120 B
    __shared__ __align__(16) float    pos_s[2][4][16][2];               //  1024 B
    __shared__ __align__(16) float    whp_s[4][68];                     //  1088 B
    __shared__ __align__(16) float    c1t7[7][64];                      //  1792 B (k-major coeffs)
    __shared__ __align__(16) float    b2s[32], b3s[32];                 //   256 B
                                                                        // total 27712 B -> 4 blocks/CU

    const int tid  = threadIdx.x;
    const int wv   = tid >> 6;
    const int lane = tid & 63;
    const int n    = lane & 15, kg = lane >> 4;
    const int bped = (blockIdx.x*2 + wv)*16;

    // prologue scratch overlaid on s2 staging (first written in warm-up,
    // after sync2; all scratch reads complete before sync2)
    float* wse_s = (float*)&s2sh[0][0][0];   // 128 floats (<= 2560 B)
    float* bse_s = wse_s + 128;              // 64
    float* sc2_s = (float*)&s2sl[0][0][0];   // 32
    float* sc3_s = sc2_s + 32;               // 32

    // ---- shared staging (all 128 threads) ----
    wse_s[tid] = Wse[tid];
    if (tid < 64) {
        bse_s[tid] = bse[tid];
        #pragma unroll
        for (int q = 0; q < 4; ++q) {   // Whp pre-permuted per kg-row
            int d = tid >> 5, jp = tid & 31, jj = jp & 15;
            int T = jj >> 3, r = (jj >> 1) & 3, col = jj & 1;
            int off = (T*16 + q*4 + r)*2 + col + ((jp >= 16) ? 64 : 0);
            whp_s[q][tid] = Whp[d*128 + off];
        }
    } else if (tid < 96) {
        const int i = tid - 64;
        b2s[i] = b2[i];
        const float* v = v2 + i*192; float s = 0.f;
        for (int j = 0; j < 192; ++j) s += v[j]*v[j];
        sc2_s[i] = g2[i] / sqrtf(s);
    } else {
        const int i = tid - 96;
        b3s[i] = b3[i];
        const float* v = v3 + i*96; float s = 0.f;
        for (int j = 0; j < 96; ++j) s += v[j]*v[j];
        sc3_s[i] = g3[i] / sqrtf(s);
    }
    __syncthreads();   // sync1: scratch + whp + biases ready

    // ---- parallel prologue fills ----
    if (wv == 0) {
        // conv1 collapse coefficients for oc = lane -> c1t7[k][oc]
        // (same values and FMA order as the verified per-oc computation)
        const float* v = v1 + lane*192; float s = 0.f;
        for (int j = 0; j < 192; ++j) s += v[j]*v[j];
        const float sc1 = g1[lane] / sqrtf(s);
        float dA0=0,dA1=0,dA2=0,dB0=0,dB1=0,dB2=0,dC0=0,dC1=0,dC2=0;
        const float* vr = v1 + lane*192;
        #pragma unroll 4
        for (int ic = 0; ic < 64; ++ic) {
            float w0 = vr[ic*3], w1 = vr[ic*3+1], w2 = vr[ic*3+2];
            float we0 = wse_s[ic*2], we1 = wse_s[ic*2+1], be = bse_s[ic];
            dA0 = fmaf(w0, we0, dA0); dB0 = fmaf(w0, we1, dB0); dC0 = fmaf(w0, be, dC0);
            dA1 = fmaf(w1, we0, dA1); dB1 = fmaf(w1, we1, dB1); dC1 = fmaf(w1, be, dC1);
            dA2 = fmaf(w2, we0, dA2); dB2 = fmaf(w2, we1, dB2); dC2 = fmaf(w2, be, dC2);
        }
        c1t7[0][lane] = sc1*dA0; c1t7[1][lane] = sc1*dB0;
        c1t7[2][lane] = sc1*dA1; c1t7[3][lane] = sc1*dB1;
        c1t7[4][lane] = sc1*dA2; c1t7[5][lane] = sc1*dB2;
        c1t7[6][lane] = fmaf(sc1, (dC0 + dC1) + dC2, b1[lane]);
    } else {
        // conv2 + conv3 LO weights -> shared LDS (same values as r11)
        #pragma unroll
        for (int f = 0; f < 12; ++f) {
            const int T = f / 6, kb = f % 6;
            const int oc = T*16 + n, tap = kb >> 1, ich = kb & 1;
            const float s2s = sc2_s[oc];
            #pragma unroll
            for (int j = 0; j < 8; ++j) {
                const int ic = ich*32 + kg*8 + j;
                float w = v2[(size_t)(oc*64 + ic)*3 + tap] * s2s;
                c2wl[f][lane][j] = f2bf(w - bf2f(f2bf(w)));
            }
        }
        #pragma unroll
        for (int f = 0; f < 6; ++f) {
            const int T = f / 3, kb = f % 3;
            const int oc = T*16 + n;
            const float s3s = sc3_s[oc];
            #pragma unroll
            for (int j = 0; j < 8; ++j) {
                const int ic = kg*8 + j;
                float w = v3[(size_t)(oc*32 + ic)*3 + kb] * s3s;
                c3wl[f][lane][j] = f2bf(w - bf2f(f2bf(w)));
            }
        }
    }
    // per-wave HI weight fragments in REGISTERS (the r4 speed factor)
    short8 c2h[2][6];
    #pragma unroll
    for (int T = 0; T < 2; ++T) {
        const int oc2 = T*16 + n;
        const float s2s = sc2_s[oc2];
        #pragma unroll
        for (int kb = 0; kb < 6; ++kb) {
            const int tap = kb >> 1, ich = kb & 1;
            #pragma unroll
            for (int j = 0; j < 8; ++j) {
                const int ic = ich*32 + kg*8 + j;
                c2h[T][kb][j] = (short)f2bf(v2[(size_t)(oc2*64 + ic)*3 + tap] * s2s);
            }
        }
    }
    short8 c3h[2][3];
    #pragma unroll
    for (int T = 0; T < 2; ++T) {
        const int oc = T*16 + n;
        const float s3s = sc3_s[oc];
        #pragma unroll
        for (int kb = 0; kb < 3; ++kb) {
            #pragma unroll
            for (int j = 0; j < 8; ++j) {
                const int ic = kg*8 + j;
                c3h[T][kb][j] = (short)f2bf(v3[(size_t)(oc*32 + ic)*3 + kb] * s3s);
            }
        }
    }
    const float bhp0 = bhp[0], bhp1 = bhp[1];
    __syncthreads();   // sync2: last barrier — scratch consumed, tables ready

    // ---- rotating per-wave state ----
    short8 s1fh[3][2], s1fl[3][2], s2fh[3], s2fl[3];
    f32x4 c3c[2][2], mxc[2][2];

    // ---- warm-up (s1 cols 0..5, conv2 0..3, conv3 0..1); all same-wave ----
    STAGE2(0); STAGE2(2);                 // taus 0..3
    C1FULL(0, 1, 2, 0);                   // col0 (t0,1,2)
    C1FULL(1, 2, 3, 1);                   // col1 (t1,2,3)
    STAGE2(4);                            // taus 4,5 -> slots 0,1
    C1FULL(2, 3, 0, 2);                   // col2 (t2,3,4)
    CONV2COL(0);                          // conv2 col0
    C1FULL(3, 0, 1, 0);                   // col3 (t3,4,5)
    CONV2COL(1);                          // conv2 col1
    STAGE2(6);                            // taus 6,7 -> slots 2,3
    C1FULL(0, 1, 2, 1);                   // col4 (t4,5,6)
    CONV2COL(2);                          // conv2 col2
    CONV3COL(0, 0);                       // conv3 col0
    C1FULL(1, 2, 3, 2);                   // col5 (t5,6,7)
    CONV2COL(0);                          // conv2 col3
    CONV3COL(1, 1);                       // conv3 col1

    // ---- 12 recurrent steps, zero barriers ----
    #pragma unroll 1
    for (int hh = 0; hh < 2; ++hh) {
        const int sbase = hh * 6;
        STEP(0); STEP(1); STEP(2); STEP(3); STEP(4); STEP(5);
    }
}

extern "C" void kernel_launch(void* const* d_in, const int* in_sizes, int n_in,
                              void* d_out, int out_size, void* d_ws, size_t ws_size,
                              hipStream_t stream)
{
    const float* obs = (const float*)d_in[0];
    // d_in[1] last_pos, d_in[2] last_pos_rel: dead state (never reaches output)
    const float* Wse = (const float*)d_in[3];
    const float* bse = (const float*)d_in[4];
    const float* v1  = (const float*)d_in[5];
    const float* g1  = (const float*)d_in[6];
    const float* b1  = (const float*)d_in[7];
    const float* v2  = (const float*)d_in[8];
    const float* g2  = (const float*)d_in[9];
    const float* b2  = (const float*)d_in[10];
    const float* v3  = (const float*)d_in[11];
    const float* g3  = (const float*)d_in[12];
    const float* b3  = (const float*)d_in[13];
    const float* Whp = (const float*)d_in[14];
    const float* bhp = (const float*)d_in[15];
    // d_in[16] seq_start_end: structurally seg = ped>>3 ; d_in[17] seq_len = 12

    enc_wp<<<NBLK, 128, 0, stream>>>(obs, Wse, bse, v1, g1, b1, v2, g2, b2,
                                     v3, g3, b3, Whp, bhp, (float*)d_out);
}

// Round 14
// 207.754 us; speedup vs baseline: 1.1599x; 1.1599x over previous
//
#include <hip/hip_runtime.h>

#define BATCH 32768
#define SEQLEN 12
#define NBLK 512   // 256 threads = 4 waves; each wave privately owns 16 peds (2 scenes)

typedef short short8 __attribute__((ext_vector_type(8)));
typedef float f32x4 __attribute__((ext_vector_type(4)));
typedef unsigned short ushort_t;

static __device__ __forceinline__ unsigned short f2bf(float x) {
    unsigned u = __float_as_uint(x);
    return (unsigned short)((u + 0x7FFFu + ((u >> 16) & 1u)) >> 16);  // RNE
}
static __device__ __forceinline__ float bf2f(unsigned short h) {
    return __uint_as_float(((unsigned)h) << 16);
}

#define MFMA __builtin_amdgcn_mfma_f32_16x16x32_bf16

// max with DPP partner (VALU). quad_perm xor1=0xB1, xor2=0x4E,
// row_half_mirror=0x141 (xor4-equivalent after xor1/xor2 for 8-lane max).
// All three verified in r13 (passed, absmax 0.001953125).
#define FMAXDPP(X, CTRL) \
    fmaxf((X), __int_as_float(__builtin_amdgcn_mov_dpp(__float_as_int(X), (CTRL), 0xF, 0xF, true)))

// Wave-private v11 = r11 (clean, 100us steady) + ONE register promotion.
// Budget model from 4 spill datapoints (r6/r8/r10/r13): at 2 waves/SIMD the
// allocator pins arch=128; spills start when arch + AGPR-eligible demand
// exceeds ~256 combined. r11 ~ 180 (clean). This round adds ONLY the conv2
// hi-weight stream as per-wave registers (+48, MFMA-feeding -> AGPR-eligible,
// est ~228): removes 12 of 24 weight b128 loads/step from the MFMA feed path
// (the r4-vs-r11 lesson: LDS loads feeding MFMA serialize the chain).
// conv2-lo (a3 compensation) stays in LDS; conv3 unchanged (hi LDS, lo regs);
// everything else byte-identical to r11. Scene-max uses the r13-verified
// 3xDPP (incl 0x141) -- fully VALU.

// ---- conv1 direct-to-fragment (r11-verified): lane (kg,n) computes its 16
// s1 elements. c1t8[oc][8] = {A0,B0,A1,B1,A2,B2,K1,pad}; per element 2
// broadcast float4 loads. FMA order identical to the verified collapse.
#define CONV1D(PA_, PB_, R0_, R1_, SL_) do {                                  \
    _Pragma("unroll")                                                         \
    for (int ich_ = 0; ich_ < 2; ++ich_) {                                    \
        const int cb_ = ich_*32 + kg*8;                                       \
        short8 sh_, sl_;                                                      \
        _Pragma("unroll")                                                     \
        for (int j_ = 0; j_ < 8; ++j_) {                                      \
            float4 c0_ = *(const float4*)&c1t8[cb_ + j_][0];                  \
            float4 c1_ = *(const float4*)&c1t8[cb_ + j_][4];                  \
            float v_ = c1_.z;                        /* K1 */                 \
            v_ = fmaf(c0_.x, (PA_).x, v_); v_ = fmaf(c0_.y, (PA_).y, v_);     \
            v_ = fmaf(c0_.z, (PB_).x, v_); v_ = fmaf(c0_.w, (PB_).y, v_);     \
            v_ = fmaf(c1_.x, (R0_), v_);   v_ = fmaf(c1_.y, (R1_), v_);       \
            v_ = fmaxf(v_, 0.f);                                              \
            ushort_t h_ = f2bf(v_);                                           \
            sh_[j_] = (short)h_;                                              \
            sl_[j_] = (short)f2bf(v_ - bf2f(h_));                             \
        }                                                                     \
        s1fh[SL_][ich_] = sh_; s1fl[SL_][ich_] = sl_;                         \
    }                                                                         \
} while(0)

// warm-up variant: third tap also from the pos ring
#define WCONV1D(SA_, SB_, SC_, SL_) do {                                      \
    float2 pa_ = *(const float2*)&pos_s[wv][SA_][n][0];                       \
    float2 pb_ = *(const float2*)&pos_s[wv][SB_][n][0];                       \
    float2 pc_ = *(const float2*)&pos_s[wv][SC_][n][0];                       \
    CONV1D(pa_, pb_, pc_.x, pc_.y, SL_);                                      \
} while(0)

// conv2 column c (c%3 == CM3): s1 reg frags x (hi REGS, lo LDS) -> s2 1-col
// stage -> reg frag slot CM3. Values identical to r11 (hi was LDS there).
#define CONV2COL(CM3) do {                                                    \
    const float* b2b_ = &b2s[0];                                              \
    asm volatile("" : "+v"(b2b_));                                            \
    _Pragma("unroll")                                                         \
    for (int T = 0; T < 2; ++T) {                                             \
        f32x4 a1 = {0.f,0.f,0.f,0.f}, a2 = {0.f,0.f,0.f,0.f},                 \
              a3 = {0.f,0.f,0.f,0.f};                                         \
        _Pragma("unroll")                                                     \
        for (int kb = 0; kb < 6; ++kb) {                                      \
            const int sl = ((CM3) + (kb >> 1)) % 3, ich = kb & 1;             \
            const short8 wl = *(const short8*)&c2wl[T*6+kb][lane][0];         \
            a1 = MFMA(c2h[T][kb], s1fh[sl][ich], a1, 0, 0, 0);                \
            a2 = MFMA(c2h[T][kb], s1fl[sl][ich], a2, 0, 0, 0);                \
            a3 = MFMA(wl, s1fh[sl][ich], a3, 0, 0, 0);                        \
        }                                                                     \
        const float4 bb = *(const float4*)&b2b_[T*16 + kg*4];                 \
        float w0 = fmaxf(a1[0]+a2[0]+a3[0]+bb.x, 0.f);                        \
        float w1 = fmaxf(a1[1]+a2[1]+a3[1]+bb.y, 0.f);                        \
        float w2 = fmaxf(a1[2]+a2[2]+a3[2]+bb.z, 0.f);                        \
        float w3 = fmaxf(a1[3]+a2[3]+a3[3]+bb.w, 0.f);                        \
        ushort_t h0=f2bf(w0), h1=f2bf(w1), h2=f2bf(w2), h3=f2bf(w3);          \
        *(uint2*)&s2sh[wv][n][T*16 + kg*4] = make_uint2(                      \
            (unsigned)h0 | ((unsigned)h1 << 16),                              \
            (unsigned)h2 | ((unsigned)h3 << 16));                             \
        *(uint2*)&s2sl[wv][n][T*16 + kg*4] = make_uint2(                      \
            (unsigned)f2bf(w0-bf2f(h0)) | ((unsigned)f2bf(w1-bf2f(h1)) << 16),\
            (unsigned)f2bf(w2-bf2f(h2)) | ((unsigned)f2bf(w3-bf2f(h3)) << 16));\
    }                                                                         \
    s2fh[(CM3)] = *(const short8*)&s2sh[wv][n][kg*8];                         \
    s2fl[(CM3)] = *(const short8*)&s2sl[wv][n][kg*8];                         \
} while(0)

// conv3 column v (v%3 == VM3, v&1 == PARI): s2 reg frags; hi weights LDS,
// lo weights regs (r11 layout). Scene-max fully VALU (r13-verified 3xDPP).
#define CONV3COL(VM3, PARI) do {                                              \
    const float* b3b_ = &b3s[0];                                              \
    asm volatile("" : "+v"(b3b_));                                            \
    _Pragma("unroll")                                                         \
    for (int T = 0; T < 2; ++T) {                                             \
        f32x4 a1 = {0.f,0.f,0.f,0.f}, a2 = {0.f,0.f,0.f,0.f},                 \
              a3 = {0.f,0.f,0.f,0.f};                                         \
        _Pragma("unroll")                                                     \
        for (int kb = 0; kb < 3; ++kb) {                                      \
            const int sl = ((VM3) + kb) % 3;                                  \
            const short8 wh = *(const short8*)&c3wh[T*3+kb][lane][0];         \
            a1 = MFMA(wh, s2fh[sl], a1, 0, 0, 0);                             \
            a2 = MFMA(wh, s2fl[sl], a2, 0, 0, 0);                             \
            a3 = MFMA(c3l[T][kb], s2fh[sl], a3, 0, 0, 0);                     \
        }                                                                     \
        const float4 b3v = *(const float4*)&b3b_[T*16 + kg*4];                \
        float m0 = fmaxf(a1[0]+a2[0]+a3[0]+b3v.x, 0.f);                       \
        float m1 = fmaxf(a1[1]+a2[1]+a3[1]+b3v.y, 0.f);                       \
        float m2 = fmaxf(a1[2]+a2[2]+a3[2]+b3v.z, 0.f);                       \
        float m3 = fmaxf(a1[3]+a2[3]+a3[3]+b3v.w, 0.f);                       \
        c3c[PARI][T] = (f32x4){m0, m1, m2, m3};                               \
        m0 = FMAXDPP(m0, 0xB1); m0 = FMAXDPP(m0, 0x4E); m0 = FMAXDPP(m0, 0x141);\
        m1 = FMAXDPP(m1, 0xB1); m1 = FMAXDPP(m1, 0x4E); m1 = FMAXDPP(m1, 0x141);\
        m2 = FMAXDPP(m2, 0xB1); m2 = FMAXDPP(m2, 0x4E); m2 = FMAXDPP(m2, 0x141);\
        m3 = FMAXDPP(m3, 0xB1); m3 = FMAXDPP(m3, 0x4E); m3 = FMAXDPP(m3, 0x141);\
        mxc[PARI][T] = (f32x4){m0, m1, m2, m3};                               \
    }                                                                         \
} while(0)

// stage obs taus T0,T0+1 into pos ring (slot = tau&3)
#define STAGE2(T0) do {                                                       \
    const int tau_ = (T0) + (lane >> 5);                                      \
    const int p_ = (lane >> 1) & 15, c_ = lane & 1;                           \
    pos_s[wv][tau_ & 3][p_][c_] =                                             \
        obs[(size_t)(tau_*BATCH + bped + p_)*2 + c_];                         \
} while(0)

// one recurrent step: h2p(st) -> conv1(st+6) -> conv2(st+4) -> conv3(st+2).
// conv1 taps preloaded FIRST (slots (st+2)&3,(st+3)&3 != written slot st&3)
// so they don't serialize behind the h2p -> pos store. (r11-verified)
#define STEP(K) do {                                                          \
    const int st = sbase + (K);                                               \
    float2 c1pa = *(const float2*)&pos_s[wv][(st+2)&3][n][0];                 \
    float2 c1pb = *(const float2*)&pos_s[wv][(st+3)&3][n][0];                 \
    float pv0a = 0.f, pv0b = 0.f, pv1a = 0.f, pv1b = 0.f;                     \
    {                                                                         \
        const float* wqf_ = &whp_s[kg][0];                                    \
        asm volatile("" : "+v"(wqf_));  /* defeat 64-reg invariant hoist */   \
        const float4* wq = (const float4*)wqf_;                               \
        _Pragma("unroll")                                                     \
        for (int q = 0; q < 16; ++q) {                                        \
            float4 ww = wq[q];                                                \
            _Pragma("unroll")                                                 \
            for (int e = 0; e < 4; ++e) {                                     \
                const int j2 = (q & 7)*4 + e;                                 \
                const int jj = j2 & 15;                                       \
                const int T = jj >> 3, r = (jj >> 1) & 3, col = jj & 1;       \
                const int par = col ? (((K)+1) & 1) : ((K) & 1);              \
                float val = (j2 < 16) ? c3c[par][T][r] : mxc[par][T][r];      \
                float wv_ = (e==0)?ww.x:(e==1)?ww.y:(e==2)?ww.z:ww.w;         \
                if (q < 8) { if (q & 1) pv0b = fmaf(wv_, val, pv0b);          \
                             else       pv0a = fmaf(wv_, val, pv0a); }        \
                else       { if (q & 1) pv1b = fmaf(wv_, val, pv1b);          \
                             else       pv1a = fmaf(wv_, val, pv1a); }        \
            }                                                                 \
        }                                                                     \
    }                                                                         \
    float pv0 = pv0a + pv0b, pv1 = pv1a + pv1b;                               \
    pv0 += __shfl_xor(pv0, 16); pv0 += __shfl_xor(pv0, 32);                   \
    pv1 += __shfl_xor(pv1, 16); pv1 += __shfl_xor(pv1, 32);                   \
    const float r0 = pv0 + bhp0, r1 = pv1 + bhp1;                             \
    if (lane < 16) {                                                          \
        float2 o; o.x = r0; o.y = r1;                                         \
        *(float2*)&out[(size_t)(st*BATCH + bped + lane)*2] = o;               \
    }                                                                         \
    if (st < SEQLEN-1) {                                                      \
        if (lane < 16) {                                                      \
            float2 o2; o2.x = r0; o2.y = r1;                                  \
            *(float2*)&pos_s[wv][st & 3][lane][0] = o2;   /* tau st+8 */      \
        }                                                                     \
        CONV1D(c1pa, c1pb, r0, r1, (K)%3);           /* col st+6 */           \
        CONV2COL(((K)+1)%3);                         /* col st+4 */           \
        CONV3COL(((K)+2)%3, (K)&1);                  /* col st+2 */           \
    }                                                                         \
} while(0)

__global__ __launch_bounds__(256, 2)
void enc_wp(const float* __restrict__ obs,
            const float* __restrict__ Wse, const float* __restrict__ bse,
            const float* __restrict__ v1, const float* __restrict__ g1, const float* __restrict__ b1,
            const float* __restrict__ v2, const float* __restrict__ g2, const float* __restrict__ b2,
            const float* __restrict__ v3, const float* __restrict__ g3, const float* __restrict__ b3,
            const float* __restrict__ Whp, const float* __restrict__ bhp,
            float* __restrict__ out)
{
    __shared__ __align__(16) ushort_t s2sh[4][16][40], s2sl[4][16][40];  // 10240 B
    __shared__ __align__(16) float    pos_s[4][4][16][2];                //  2048 B
    __shared__ __align__(16) float    whp_s[4][68];                      //  1088 B (padded)
    __shared__ __align__(16) ushort_t c2wl[12][64][8];                   // 12288 B (lo only)
    __shared__ __align__(16) ushort_t c3wh[6][64][8];                    //  6144 B (hi)
    __shared__ __align__(16) float    b2s[32], b3s[32];                  //   256 B
    __shared__ __align__(16) float    c1t8[64][8];                       //  2048 B (oc-major coeffs)
                                                                         // total 34112 B

    const int tid  = threadIdx.x;
    const int wv   = tid >> 6;
    const int lane = tid & 63;
    const int n    = lane & 15, kg = lane >> 4;
    const int bped = (blockIdx.x*4 + wv)*16;

    // prologue scratch overlaid on s2 staging (dead until warm-up conv2,
    // which is after sync2; all scratch reads complete before sync2)
    float* scr   = (float*)&s2sh[0][0][0];
    float* wse_s = scr;          // 128
    float* bse_s = scr + 128;    // 64
    float* sc2_s = scr + 192;    // 32
    float* sc3_s = scr + 224;    // 32

    // ---- shared staging (wave 0) ----
    if (wv == 0) {
        wse_s[lane] = Wse[lane]; wse_s[64 + lane] = Wse[64 + lane];
        bse_s[lane] = bse[lane];
        if (lane < 32) {
            b2s[lane] = b2[lane];
            const float* v = v2 + lane*192; float s = 0.f;
            for (int j = 0; j < 192; ++j) s += v[j]*v[j];
            sc2_s[lane] = g2[lane] / sqrtf(s);
        } else {
            b3s[lane-32] = b3[lane-32];
            const float* v = v3 + (lane-32)*96; float s = 0.f;
            for (int j = 0; j < 96; ++j) s += v[j]*v[j];
            sc3_s[lane-32] = g3[lane-32] / sqrtf(s);
        }
        #pragma unroll
        for (int q = 0; q < 4; ++q) {   // Whp pre-permuted per kg-row
            int d = lane >> 5, jp = lane & 31, jj = jp & 15;
            int T = jj >> 3, r = (jj >> 1) & 3, col = jj & 1;
            int off = (T*16 + q*4 + r)*2 + col + ((jp >= 16) ? 64 : 0);
            whp_s[q][lane] = Whp[d*128 + off];
        }
    }
    __syncthreads();   // sync1: scratch + whp + biases ready

    // ---- parallel prologue fills ----
    if (wv == 0) {
        // conv1 collapse coefficients for oc = lane -> c1t8[oc] (same values
        // and FMA order as the verified per-oc computation)
        const float* v = v1 + lane*192; float s = 0.f;
        for (int j = 0; j < 192; ++j) s += v[j]*v[j];
        const float sc1 = g1[lane] / sqrtf(s);
        float dA0=0,dA1=0,dA2=0,dB0=0,dB1=0,dB2=0,dC0=0,dC1=0,dC2=0;
        const float* vr = v1 + lane*192;
        #pragma unroll 4
        for (int ic = 0; ic < 64; ++ic) {
            float w0 = vr[ic*3], w1 = vr[ic*3+1], w2 = vr[ic*3+2];
            float we0 = wse_s[ic*2], we1 = wse_s[ic*2+1], be = bse_s[ic];
            dA0 = fmaf(w0, we0, dA0); dB0 = fmaf(w0, we1, dB0); dC0 = fmaf(w0, be, dC0);
            dA1 = fmaf(w1, we0, dA1); dB1 = fmaf(w1, we1, dB1); dC1 = fmaf(w1, be, dC1);
            dA2 = fmaf(w2, we0, dA2); dB2 = fmaf(w2, we1, dB2); dC2 = fmaf(w2, be, dC2);
        }
        c1t8[lane][0] = sc1*dA0; c1t8[lane][1] = sc1*dB0;
        c1t8[lane][2] = sc1*dA1; c1t8[lane][3] = sc1*dB1;
        c1t8[lane][4] = sc1*dA2; c1t8[lane][5] = sc1*dB2;
        c1t8[lane][6] = fmaf(sc1, (dC0 + dC1) + dC2, b1[lane]);
        c1t8[lane][7] = 0.f;
    } else if (wv == 2) {          // conv2 LO weights -> LDS (a3 path only)
        #pragma unroll
        for (int f = 0; f < 12; ++f) {
            const int T = f / 6, kb = f % 6;
            const int oc = T*16 + n, tap = kb >> 1, ich = kb & 1;
            const float s2s = sc2_s[oc];
            #pragma unroll
            for (int j = 0; j < 8; ++j) {
                const int ic = ich*32 + kg*8 + j;
                float w = v2[(size_t)(oc*64 + ic)*3 + tap] * s2s;
                c2wl[f][lane][j] = f2bf(w - bf2f(f2bf(w)));
            }
        }
    } else if (wv == 1) {          // conv3 hi weights -> LDS
        #pragma unroll
        for (int f = 0; f < 6; ++f) {
            const int T = f / 3, kb = f % 3;
            const int oc = T*16 + n;
            const float s3s = sc3_s[oc];
            #pragma unroll
            for (int j = 0; j < 8; ++j) {
                const int ic = kg*8 + j;
                c3wh[f][lane][j] = f2bf(v3[(size_t)(oc*32 + ic)*3 + kb] * s3s);
            }
        }
    }
    // conv2 HI weight fragments -> per-wave REGISTERS (AGPR-eligible; the
    // single promotion this round). Values identical to r11's c2wh content.
    short8 c2h[2][6];
    #pragma unroll
    for (int T = 0; T < 2; ++T) {
        const int oc2 = T*16 + n;
        const float s2s = sc2_s[oc2];
        #pragma unroll
        for (int kb = 0; kb < 6; ++kb) {
            const int tap = kb >> 1, ich = kb & 1;
            #pragma unroll
            for (int j = 0; j < 8; ++j) {
                const int ic = ich*32 + kg*8 + j;
                c2h[T][kb][j] = (short)f2bf(v2[(size_t)(oc2*64 + ic)*3 + tap] * s2s);
            }
        }
    }
    // conv3 LO weight fragments (per-wave registers; r11 layout)
    short8 c3l[2][3];
    #pragma unroll
    for (int T = 0; T < 2; ++T) {
        const int oc = T*16 + n;
        const float s3s = sc3_s[oc];
        #pragma unroll
        for (int kb = 0; kb < 3; ++kb) {
            #pragma unroll
            for (int j = 0; j < 8; ++j) {
                const int ic = kg*8 + j;
                float w = v3[(size_t)(oc*32 + ic)*3 + kb] * s3s;
                c3l[T][kb][j] = (short)f2bf(w - bf2f(f2bf(w)));
            }
        }
    }
    const float bhp0 = bhp[0], bhp1 = bhp[1];
    __syncthreads();   // sync2: last barrier — scratch consumed, tables ready

    // ---- rotating per-wave state ----
    short8 s1fh[3][2], s1fl[3][2], s2fh[3], s2fl[3];
    f32x4 c3c[2][2], mxc[2][2];

    // ---- warm-up (s1 cols 0..5, conv2 0..3, conv3 0..1); all same-wave ----
    STAGE2(0); STAGE2(2);                 // taus 0..3
    WCONV1D(0, 1, 2, 0);                  // col0 (t0,1,2)
    WCONV1D(1, 2, 3, 1);                  // col1 (t1,2,3)
    STAGE2(4);                            // taus 4,5 -> slots 0,1
    WCONV1D(2, 3, 0, 2);                  // col2 (t2,3,4)
    CONV2COL(0);                          // conv2 col0
    WCONV1D(3, 0, 1, 0);                  // col3 (t3,4,5)
    CONV2COL(1);                          // conv2 col1
    STAGE2(6);                            // taus 6,7 -> slots 2,3
    WCONV1D(0, 1, 2, 1);                  // col4 (t4,5,6)
    CONV2COL(2);                          // conv2 col2
    CONV3COL(0, 0);                       // conv3 col0
    WCONV1D(1, 2, 3, 2);                  // col5 (t5,6,7)
    CONV2COL(0);                          // conv2 col3
    CONV3COL(1, 1);                       // conv3 col1

    // ---- 12 recurrent steps, zero barriers ----
    #pragma unroll 1
    for (int hh = 0; hh < 2; ++hh) {
        const int sbase = hh * 6;
        STEP(0); STEP(1); STEP(2); STEP(3); STEP(4); STEP(5);
    }
}

extern "C" void kernel_launch(void* const* d_in, const int* in_sizes, int n_in,
                              void* d_out, int out_size, void* d_ws, size_t ws_size,
                              hipStream_t stream)
{
    const float* obs = (const float*)d_in[0];
    // d_in[1] last_pos, d_in[2] last_pos_rel: dead state (never reaches output)
    const float* Wse = (const float*)d_in[3];
    const float* bse = (const float*)d_in[4];
    const float* v1  = (const float*)d_in[5];
    const float* g1  = (const float*)d_in[6];
    const float* b1  = (const float*)d_in[7];
    const float* v2  = (const float*)d_in[8];
    const float* g2  = (const float*)d_in[9];
    const float* b2  = (const float*)d_in[10];
    const float* v3  = (const float*)d_in[11];
    const float* g3  = (const float*)d_in[12];
    const float* b3  = (const float*)d_in[13];
    const float* Whp = (const float*)d_in[14];
    const float* bhp = (const float*)d_in[15];
    // d_in[16] seq_start_end: structurally seg = ped>>3 ; d_in[17] seq_len = 12

    enc_wp<<<NBLK, 256, 0, stream>>>(obs, Wse, bse, v1, g1, b1, v2, g2, b2,
                                     v3, g3, b3, Whp, bhp, (float*)d_out);
}